// Round 6
// baseline (110.730 us; speedup 1.0000x reference)
//
#include <hip/hip_runtime.h>
#include <math.h>

#define D 512
#define NB_P 2048   // partial-bag blocks (8 blocks/CU x 4 waves = full occupancy)

// ---------------- K1: dot[j] = features[j] . attn_w  (one wave per row) ----
// R1-proven version: 4 waves/block, 1 row per wave. DO NOT TOUCH.
__global__ void k_dot(const float* __restrict__ f, const float* __restrict__ w,
                      float* __restrict__ dot, int n) {
    int wave = threadIdx.x >> 6;            // 4 waves / block
    int lane = threadIdx.x & 63;
    int row  = blockIdx.x * 4 + wave;
    if (row >= n) return;
    const float4* fr = (const float4*)(f + (size_t)row * D);
    const float4* wr = (const float4*)w;
    float4 a0 = fr[lane],      b0 = wr[lane];
    float4 a1 = fr[lane + 64], b1 = wr[lane + 64];
    float s = a0.x*b0.x + a0.y*b0.y + a0.z*b0.z + a0.w*b0.w
            + a1.x*b1.x + a1.y*b1.y + a1.z*b1.z + a1.w*b1.w;
    #pragma unroll
    for (int off = 32; off; off >>= 1) s += __shfl_down(s, off);
    if (lane == 0) dot[row] = s;
}

// ------- K2: scores + per-block softmax partials (m_b, s_b) ----------------
__global__ void k_scores(const float* __restrict__ dot, const float* __restrict__ bptr,
                         const int* __restrict__ kptr, float* __restrict__ scores,
                         float* __restrict__ pmax, float* __restrict__ psum, int n) {
    int i = blockIdx.x * 256 + threadIdx.x;
    int k = *kptr;
    float val = -INFINITY;
    if (i < n) {
        int lo = max(i - k, 0), hi = min(i + k, n - 1);
        float s = 0.f;
        for (int j = lo; j <= hi; ++j) s += dot[j];
        val = s / (float)(hi - lo + 1) + bptr[0];
        scores[i] = val;
    }
    __shared__ float sm[4];
    __shared__ float bmax;
    int lane = threadIdx.x & 63, wid = threadIdx.x >> 6;
    float m = val;
    #pragma unroll
    for (int off = 32; off; off >>= 1) m = fmaxf(m, __shfl_down(m, off));
    if (lane == 0) sm[wid] = m;
    __syncthreads();
    if (threadIdx.x == 0)
        bmax = fmaxf(fmaxf(sm[0], sm[1]), fmaxf(sm[2], sm[3]));
    __syncthreads();
    float mb = bmax;
    float e = (i < n) ? __expf(val - mb) : 0.f;
    #pragma unroll
    for (int off = 32; off; off >>= 1) e += __shfl_down(e, off);
    __syncthreads();               // sm reuse guard
    if (lane == 0) sm[wid] = e;
    __syncthreads();
    if (threadIdx.x == 0) {
        pmax[blockIdx.x] = mb;
        psum[blockIdx.x] = sm[0] + sm[1] + sm[2] + sm[3];
    }
}

// ---- K3: inline-combine partials, then w[j] and u[j] ------------------------
// u[j] = inv * sum_{i in win(j)} exp(scores[i]-gmax)/cnt(i)
__global__ void k_wu(const float* __restrict__ scores, const float* __restrict__ pmax,
                     const float* __restrict__ psum, int nb1,
                     const int* __restrict__ kptr, float* __restrict__ w_out,
                     float* __restrict__ u, int n) {
    __shared__ float sm[4];
    __shared__ float gshared[2];
    int lane = threadIdx.x & 63, wid = threadIdx.x >> 6;

    // global max (each block redundantly reduces nb1 entries — L2-hit, ~3 KB)
    float m = -INFINITY;
    for (int idx = threadIdx.x; idx < nb1; idx += 256) m = fmaxf(m, pmax[idx]);
    #pragma unroll
    for (int off = 32; off; off >>= 1) m = fmaxf(m, __shfl_down(m, off));
    if (lane == 0) sm[wid] = m;
    __syncthreads();
    if (threadIdx.x == 0)
        gshared[0] = fmaxf(fmaxf(sm[0], sm[1]), fmaxf(sm[2], sm[3]));
    __syncthreads();
    float gmax = gshared[0];

    // global sum
    float s = 0.f;
    for (int idx = threadIdx.x; idx < nb1; idx += 256)
        s += psum[idx] * __expf(pmax[idx] - gmax);
    #pragma unroll
    for (int off = 32; off; off >>= 1) s += __shfl_down(s, off);
    __syncthreads();               // sm reuse guard
    if (lane == 0) sm[wid] = s;
    __syncthreads();
    if (threadIdx.x == 0)
        gshared[1] = 1.f / (sm[0] + sm[1] + sm[2] + sm[3]);
    __syncthreads();
    float inv = gshared[1];

    int j = blockIdx.x * 256 + threadIdx.x;
    if (j >= n) return;
    int k = *kptr;
    float ej = __expf(scores[j] - gmax);
    w_out[j] = ej * inv;
    int lo = max(j - k, 0), hi = min(j + k, n - 1);
    float acc = 0.f;
    for (int i = lo; i <= hi; ++i) {
        int li = max(i - k, 0), hh = min(i + k, n - 1);
        float e = __expf(scores[i] - gmax);
        acc += e * __builtin_amdgcn_rcpf((float)(hh - li + 1));
    }
    u[j] = acc * inv;
}

// ---- K4: partial bag, 256 threads = 2 row-groups x 128 cols, unroll 2 ------
__global__ __launch_bounds__(256) void k_pbag(
    const float* __restrict__ f, const float* __restrict__ u,
    float* __restrict__ partial, int n, int chunk)
{
    int t  = threadIdx.x & 127;     // float4 column index (128 x 4 = 512 cols)
    int rg = threadIdx.x >> 7;      // row-group 0: even rows, 1: odd rows
    int j0 = blockIdx.x * chunk;
    int j1 = min(j0 + chunk, n);

    float4 acc0 = make_float4(0.f, 0.f, 0.f, 0.f);
    float4 acc1 = make_float4(0.f, 0.f, 0.f, 0.f);

    int j = j0 + rg;
    for (; j + 2 < j1; j += 4) {    // process j and j+2 (both in this rg)
        float ua = u[j], ub = u[j + 2];
        float4 va = ((const float4*)(f + (size_t)j       * D))[t];
        float4 vb = ((const float4*)(f + (size_t)(j + 2) * D))[t];
        acc0.x += ua*va.x; acc0.y += ua*va.y; acc0.z += ua*va.z; acc0.w += ua*va.w;
        acc1.x += ub*vb.x; acc1.y += ub*vb.y; acc1.z += ub*vb.z; acc1.w += ub*vb.w;
    }
    for (; j < j1; j += 2) {
        float ua = u[j];
        float4 va = ((const float4*)(f + (size_t)j * D))[t];
        acc0.x += ua*va.x; acc0.y += ua*va.y; acc0.z += ua*va.z; acc0.w += ua*va.w;
    }

    float4 a;
    a.x = acc0.x + acc1.x; a.y = acc0.y + acc1.y;
    a.z = acc0.z + acc1.z; a.w = acc0.w + acc1.w;

    __shared__ float4 smem[128];
    if (rg == 1) smem[t] = a;
    __syncthreads();
    if (rg == 0) {
        float4 b = smem[t];
        a.x += b.x; a.y += b.y; a.z += b.z; a.w += b.w;
        ((float4*)(partial + (size_t)blockIdx.x * D))[t] = a;
    }
}

// ---------------- K5: reduce partial[NB_P][512] -> bag[512] -----------------
__global__ void k_rbag(const float* __restrict__ partial, float* __restrict__ bag, int nb) {
    int c = blockIdx.x * 16 + (threadIdx.x & 15);   // 32 blocks x 16 cols
    int r = threadIdx.x >> 4;                       // 16 row-groups
    float acc = 0.f;
    for (int b = r; b < nb; b += 16) acc += partial[(size_t)b * D + c];
    __shared__ float sm[256];
    sm[threadIdx.x] = acc;
    __syncthreads();
    if (threadIdx.x < 16) {
        float s = 0.f;
        #pragma unroll
        for (int q = 0; q < 16; ++q) s += sm[q * 16 + threadIdx.x];
        bag[blockIdx.x * 16 + threadIdx.x] = s;
    }
}

extern "C" void kernel_launch(void* const* d_in, const int* in_sizes, int n_in,
                              void* d_out, int out_size, void* d_ws, size_t ws_size,
                              hipStream_t stream) {
    const float* f  = (const float*)d_in[0];
    const float* aw = (const float*)d_in[1];
    const float* ab = (const float*)d_in[2];
    const int*   kp = (const int*)d_in[3];
    int n = in_sizes[0] / D;

    float* bag   = (float*)d_out;        // [512]
    float* w_out = (float*)d_out + D;    // [n]

    int nb2 = (n + 255) / 256;           // 391 blocks for scores / wu

    float* wsf     = (float*)d_ws;
    float* dot     = wsf;                        // n
    float* scores  = wsf + n;                    // n
    float* u       = wsf + 2 * (size_t)n;        // n
    float* pmax    = wsf + 3 * (size_t)n;        // nb2
    float* psum    = pmax + nb2;                 // nb2
    size_t poff    = ((3 * (size_t)n + 2 * (size_t)nb2) + 31) & ~(size_t)31;
    float* partial = wsf + poff;                 // NB_P * D

    int chunk = (n + NB_P - 1) / NB_P;

    k_dot   <<<(n + 3) / 4, 256, 0, stream>>>(f, aw, dot, n);
    k_scores<<<nb2, 256, 0, stream>>>(dot, ab, kp, scores, pmax, psum, n);
    k_wu    <<<nb2, 256, 0, stream>>>(scores, pmax, psum, nb2, kp, w_out, u, n);
    k_pbag  <<<NB_P, 256, 0, stream>>>(f, u, partial, n, chunk);
    k_rbag  <<<32, 256, 0, stream>>>(partial, bag, NB_P);
}